// Round 12
// baseline (612.645 us; speedup 1.0000x reference)
//
#include <hip/hip_runtime.h>
#include <hip/hip_bf16.h>

#define N_NODES 50000
#define N_EDGES 800000
#define N_GRAPHS 500
#define IN_DIM 128
#define HID 64
#define OUT_DIM 10
#define NB_BUCK ((N_NODES + 63) >> 6)  // 782 buckets of 64 nodes
#define NBLK 128                       // edge chunks (~6250 edges each)
#define BLDT 512                       // build-kernel block size

// ---- bf16 helpers: exact expand on load, RNE on store ----
__device__ __forceinline__ float bf2f(unsigned short u) {
    return __uint_as_float(((unsigned)u) << 16);
}
__device__ __forceinline__ unsigned short f2bf(float f) {
    unsigned x = __float_as_uint(f);
    x += 0x7fffu + ((x >> 16) & 1u);  // round-to-nearest-even
    return (unsigned short)(x >> 16);
}

// ---------------- P1: per-chunk bucket histogram (LDS, no global atomics) ----------------
__global__ __launch_bounds__(BLDT) void p1_hist_kernel(const int* __restrict__ dst,
                                                       int* __restrict__ bhist, int e, int epb) {
    __shared__ int h[NB_BUCK];
    int tid = threadIdx.x;
    int blk = blockIdx.x;
    for (int i = tid; i < NB_BUCK; i += BLDT) h[i] = 0;
    __syncthreads();
    int e0 = blk * epb;
    int e1 = e0 + epb;
    if (e1 > e) e1 = e;
    for (int i = e0 + tid; i < e1; i += BLDT) atomicAdd(&h[dst[i] >> 6], 1);
    __syncthreads();
    for (int i = tid; i < NB_BUCK; i += BLDT) bhist[blk * NB_BUCK + i] = h[i];
}

// ---- scanA: per bucket, scan NBLK chunk counts IN PLACE (bhist -> exclusive bases) + total ----
__global__ __launch_bounds__(NBLK) void scanA_kernel(int* __restrict__ bhist,
                                                     int* __restrict__ bsum) {
    __shared__ int s[NBLK];
    int b = blockIdx.x;
    int t = threadIdx.x;  // NBLK threads
    int c = bhist[t * NB_BUCK + b];
    s[t] = c;
    __syncthreads();
    for (int off = 1; off < NBLK; off <<= 1) {
        int x = (t >= off) ? s[t - off] : 0;
        __syncthreads();
        s[t] += x;
        __syncthreads();
    }
    bhist[t * NB_BUCK + b] = s[t] - c;  // in-place: exclusive prefix for chunk t
    if (t == NBLK - 1) bsum[b] = s[t];
}

// ---------------- bscan: exclusive scan over bucket totals ----------------
__global__ __launch_bounds__(1024) void bscan_kernel(const int* __restrict__ bsum,
                                                     int* __restrict__ bstart, int nb, int e) {
    __shared__ int s[1024];
    int t = threadIdx.x;
    int v = (t < nb) ? bsum[t] : 0;
    s[t] = v;
    __syncthreads();
    for (int off = 1; off < 1024; off <<= 1) {
        int x = (t >= off) ? s[t - off] : 0;
        __syncthreads();
        s[t] += x;
        __syncthreads();
    }
    if (t < nb) bstart[t] = s[t] - v;
    if (t == 0) bstart[nb] = e;
}

// ---------------- P2: place edges into bucket-grouped pairs (block-local dense segments) ------
__global__ __launch_bounds__(BLDT) void p2_place_kernel(
    const int* __restrict__ src, const int* __restrict__ dst, const int* __restrict__ bstart,
    const int* __restrict__ base, unsigned* __restrict__ pairs, int e, int epb) {
    __shared__ int h[NB_BUCK];   // local rank counters
    __shared__ int sb[NB_BUCK];  // global segment base for this chunk
    int tid = threadIdx.x;
    int blk = blockIdx.x;
    for (int i = tid; i < NB_BUCK; i += BLDT) {
        h[i] = 0;
        sb[i] = bstart[i] + base[blk * NB_BUCK + i];
    }
    __syncthreads();
    int e0 = blk * epb;
    int e1 = e0 + epb;
    if (e1 > e) e1 = e;
    for (int i = e0 + tid; i < e1; i += BLDT) {
        int d = dst[i];
        int b = d >> 6;
        int r = atomicAdd(&h[b], 1);
        pairs[sb[b] + r] = ((unsigned)(d & 63) << 16) | (unsigned)src[i];
    }
}

// ---------------- csr_scatter2: per bucket -> rs, dinv, csr_src (no global atomics) ----------
__global__ __launch_bounds__(256) void csr_scatter2_kernel(
    const unsigned* __restrict__ pairs, const int* __restrict__ bstart,
    int* __restrict__ rs, float* __restrict__ dinv, int* __restrict__ csr_src, int n) {
    __shared__ int lcnt[64];
    __shared__ int lcur[64];
    int b = blockIdx.x;
    int tid = threadIdx.x;
    int beg = bstart[b], end = bstart[b + 1];
    if (tid < 64) lcnt[tid] = 0;
    __syncthreads();
    for (int i = beg + tid; i < end; i += 256) atomicAdd(&lcnt[pairs[i] >> 16], 1);
    __syncthreads();
    if (tid < 64) {  // wave 0: scan the 64 node counts
        int c = lcnt[tid];
        int v = c;
#pragma unroll
        for (int off = 1; off < 64; off <<= 1) {
            int t = __shfl_up(v, off);
            if (tid >= off) v += t;
        }
        int excl = v - c;
        int node = b * 64 + tid;
        if (node <= n) {
            rs[node] = beg + excl;  // node==n lands on rs[N]=E (last bucket's tail)
            if (node < n) dinv[node] = rsqrtf((float)(c + 1));
        }
        lcur[tid] = beg + excl;
    }
    __syncthreads();
    for (int i = beg + tid; i < end; i += 256) {
        unsigned p = pairs[i];
        int slot = atomicAdd(&lcur[p >> 16], 1);
        csr_src[slot] = (int)(p & 0xffffu);
    }
}

// ---------------- layer-1 linear: fp32 A (K=128) -> bf16 hs (+ dinv pre-scale) ----------------
__global__ __launch_bounds__(256) void linear1_kernel(
    const float* __restrict__ A, const float* __restrict__ W,
    const float* __restrict__ dinv, unsigned short* __restrict__ C, int n) {
    const int K = IN_DIM;
    __shared__ float As[64][K + 4];
    __shared__ float Ws[K][64];
    int tid = threadIdx.x;
    int tx = tid & 15;
    int ty = tid >> 4;
    int block0 = blockIdx.x * 64;
    int rows = n - block0;
    if (rows > 64) rows = 64;

    const float* Abase = A + (size_t)block0 * K;
    int totalA4 = (rows * K) >> 2;
    for (int i4 = tid; i4 < totalA4; i4 += 256) {
        int i = i4 << 2;
        float4 v = *(const float4*)(Abase + i);
        *(float4*)&As[i / K][i % K] = v;
    }
    {
        const float4* Wv = (const float4*)W;
        float4* Wsv = (float4*)&Ws[0][0];
        for (int i = tid; i < K * 16; i += 256) Wsv[i] = Wv[i];
    }
    __syncthreads();

    float acc[4][4] = {};
#pragma unroll 2
    for (int k = 0; k < K; k += 4) {
        float4 a[4];
#pragma unroll
        for (int i = 0; i < 4; ++i) a[i] = *(const float4*)&As[ty * 4 + i][k];
        float4 w[4];
#pragma unroll
        for (int kk = 0; kk < 4; ++kk) w[kk] = *(const float4*)&Ws[k + kk][tx * 4];
#pragma unroll
        for (int i = 0; i < 4; ++i) {
            float av[4] = {a[i].x, a[i].y, a[i].z, a[i].w};
#pragma unroll
            for (int kk = 0; kk < 4; ++kk) {
                acc[i][0] += av[kk] * w[kk].x;
                acc[i][1] += av[kk] * w[kk].y;
                acc[i][2] += av[kk] * w[kk].z;
                acc[i][3] += av[kk] * w[kk].w;
            }
        }
    }

#pragma unroll
    for (int i = 0; i < 4; ++i) {
        int r = ty * 4 + i;
        if (r < rows) {
            float s = dinv[block0 + r];
            ushort4 v;
            v.x = f2bf(acc[i][0] * s);
            v.y = f2bf(acc[i][1] * s);
            v.z = f2bf(acc[i][2] * s);
            v.w = f2bf(acc[i][3] * s);
            *(ushort4*)&C[(size_t)(block0 + r) * 64 + tx * 4] = v;
        }
    }
}

// ---- fused: per-node bf16 gather (+bias+relu, fp32 row in LDS) THEN mini-GEMM with Wnext ----
// outp[node][f] = dinv[node] * sum_k h[node][k] * Wnext[k][f],  h = relu(dinv*Σhs + bias)
__global__ __launch_bounds__(256) void gather_linear_kernel(
    const unsigned short* __restrict__ hs, const int* __restrict__ rs,
    const int* __restrict__ csr_src, const float* __restrict__ dinv,
    const float* __restrict__ bias, const float* __restrict__ Wnext,
    unsigned short* __restrict__ outp, int n) {
    __shared__ float Ws[64][64];  // 16 KB: Wnext staged
    __shared__ float p4[4][68];   // post-relu h rows (fp32); [64] = dinv[node]
    int tid = threadIdx.x;
    // stage Wnext (64x64 fp32 = 1024 float4); hidden under the gather latency below
    {
        const float4* Wv = (const float4*)Wnext;
        float4* Wsv = (float4*)&Ws[0][0];
        for (int i = tid; i < 1024; i += 256) Wsv[i] = Wv[i];
    }
    int wave = tid >> 6;
    int node = blockIdx.x * 4 + wave;
    int lane = tid & 63;
    int eg = lane >> 4;         // edge group 0..3
    int f4 = (lane & 15) << 2;  // feature quad
    bool valid = node < n;
    float4 acc = {0.f, 0.f, 0.f, 0.f};
    float dv = 0.f;
    if (valid) {
        dv = dinv[node];
        int beg = rs[node], end = rs[node + 1];
        if (eg == 0) {  // self-loop (pre-scaled)
            ushort4 u = *(const ushort4*)&hs[(size_t)node * 64 + f4];
            acc.x = bf2f(u.x); acc.y = bf2f(u.y); acc.z = bf2f(u.z); acc.w = bf2f(u.w);
        }
        int j = beg + eg;
        for (; j + 12 < end; j += 16) {  // 4 rows in flight per lane-group
            int s0 = csr_src[j];
            int s1 = csr_src[j + 4];
            int s2 = csr_src[j + 8];
            int s3 = csr_src[j + 12];
            ushort4 u0 = *(const ushort4*)&hs[(size_t)s0 * 64 + f4];
            ushort4 u1 = *(const ushort4*)&hs[(size_t)s1 * 64 + f4];
            ushort4 u2 = *(const ushort4*)&hs[(size_t)s2 * 64 + f4];
            ushort4 u3 = *(const ushort4*)&hs[(size_t)s3 * 64 + f4];
            acc.x += bf2f(u0.x) + bf2f(u1.x) + bf2f(u2.x) + bf2f(u3.x);
            acc.y += bf2f(u0.y) + bf2f(u1.y) + bf2f(u2.y) + bf2f(u3.y);
            acc.z += bf2f(u0.z) + bf2f(u1.z) + bf2f(u2.z) + bf2f(u3.z);
            acc.w += bf2f(u0.w) + bf2f(u1.w) + bf2f(u2.w) + bf2f(u3.w);
        }
        for (; j < end; j += 4) {
            int s = csr_src[j];
            ushort4 u = *(const ushort4*)&hs[(size_t)s * 64 + f4];
            acc.x += bf2f(u.x); acc.y += bf2f(u.y); acc.z += bf2f(u.z); acc.w += bf2f(u.w);
        }
        // merge the 4 edge groups: butterfly over lane bits 4,5
        acc.x += __shfl_xor(acc.x, 16); acc.y += __shfl_xor(acc.y, 16);
        acc.z += __shfl_xor(acc.z, 16); acc.w += __shfl_xor(acc.w, 16);
        acc.x += __shfl_xor(acc.x, 32); acc.y += __shfl_xor(acc.y, 32);
        acc.z += __shfl_xor(acc.z, 32); acc.w += __shfl_xor(acc.w, 32);
    }
    if (eg == 0) {  // write post-relu h row (fp32) + dinv to LDS
        float4 bb = {0.f, 0.f, 0.f, 0.f};
        if (valid) bb = *(const float4*)&bias[f4];
        float4 o;
        o.x = fmaxf(acc.x * dv + bb.x, 0.f);
        o.y = fmaxf(acc.y * dv + bb.y, 0.f);
        o.z = fmaxf(acc.z * dv + bb.z, 0.f);
        o.w = fmaxf(acc.w * dv + bb.w, 0.f);
        if (!valid) { o.x = o.y = o.z = o.w = 0.f; }
        *(float4*)&p4[wave][f4] = o;
        if (lane == 0) p4[wave][64] = dv;
    }
    __syncthreads();
    if (wave == 0) {  // mini-GEMM: 4 nodes x 64 feats, register-blocked over nodes
        int f = lane;
        float a0 = 0.f, a1 = 0.f, a2 = 0.f, a3 = 0.f;
#pragma unroll
        for (int k4 = 0; k4 < 16; ++k4) {
            int k = k4 * 4;
            float w0 = Ws[k + 0][f];
            float w1 = Ws[k + 1][f];
            float w2 = Ws[k + 2][f];
            float w3 = Ws[k + 3][f];
            float4 q0 = *(const float4*)&p4[0][k];  // broadcast reads
            float4 q1 = *(const float4*)&p4[1][k];
            float4 q2 = *(const float4*)&p4[2][k];
            float4 q3 = *(const float4*)&p4[3][k];
            a0 += q0.x * w0 + q0.y * w1 + q0.z * w2 + q0.w * w3;
            a1 += q1.x * w0 + q1.y * w1 + q1.z * w2 + q1.w * w3;
            a2 += q2.x * w0 + q2.y * w1 + q2.z * w2 + q2.w * w3;
            a3 += q3.x * w0 + q3.y * w1 + q3.z * w2 + q3.w * w3;
        }
        int base = blockIdx.x * 4;
        if (base + 0 < n) outp[(size_t)(base + 0) * 64 + f] = f2bf(a0 * p4[0][64]);
        if (base + 1 < n) outp[(size_t)(base + 1) * 64 + f] = f2bf(a1 * p4[1][64]);
        if (base + 2 < n) outp[(size_t)(base + 2) * 64 + f] = f2bf(a2 * p4[2][64]);
        if (base + 3 < n) outp[(size_t)(base + 3) * 64 + f] = f2bf(a3 * p4[3][64]);
    }
}

// ------- last-layer gather: bf16 in/out, fp32 accumulate; fused self-loop+bias+relu ----------
__global__ __launch_bounds__(256) void gather_kernel(
    const unsigned short* __restrict__ hs, const int* __restrict__ rs,
    const int* __restrict__ csr_src, const float* __restrict__ dinv,
    const float* __restrict__ bias, unsigned short* __restrict__ outp, int n) {
    int wave = threadIdx.x >> 6;
    int node = blockIdx.x * 4 + wave;
    if (node >= n) return;
    int lane = threadIdx.x & 63;
    int eg = lane >> 4;
    int f4 = (lane & 15) << 2;
    int beg = rs[node], end = rs[node + 1];
    float4 acc = {0.f, 0.f, 0.f, 0.f};
    if (eg == 0) {
        ushort4 u = *(const ushort4*)&hs[(size_t)node * 64 + f4];
        acc.x = bf2f(u.x); acc.y = bf2f(u.y); acc.z = bf2f(u.z); acc.w = bf2f(u.w);
    }
    int j = beg + eg;
    for (; j + 12 < end; j += 16) {
        int s0 = csr_src[j];
        int s1 = csr_src[j + 4];
        int s2 = csr_src[j + 8];
        int s3 = csr_src[j + 12];
        ushort4 u0 = *(const ushort4*)&hs[(size_t)s0 * 64 + f4];
        ushort4 u1 = *(const ushort4*)&hs[(size_t)s1 * 64 + f4];
        ushort4 u2 = *(const ushort4*)&hs[(size_t)s2 * 64 + f4];
        ushort4 u3 = *(const ushort4*)&hs[(size_t)s3 * 64 + f4];
        acc.x += bf2f(u0.x) + bf2f(u1.x) + bf2f(u2.x) + bf2f(u3.x);
        acc.y += bf2f(u0.y) + bf2f(u1.y) + bf2f(u2.y) + bf2f(u3.y);
        acc.z += bf2f(u0.z) + bf2f(u1.z) + bf2f(u2.z) + bf2f(u3.z);
        acc.w += bf2f(u0.w) + bf2f(u1.w) + bf2f(u2.w) + bf2f(u3.w);
    }
    for (; j < end; j += 4) {
        int s = csr_src[j];
        ushort4 u = *(const ushort4*)&hs[(size_t)s * 64 + f4];
        acc.x += bf2f(u.x); acc.y += bf2f(u.y); acc.z += bf2f(u.z); acc.w += bf2f(u.w);
    }
    acc.x += __shfl_xor(acc.x, 16); acc.y += __shfl_xor(acc.y, 16);
    acc.z += __shfl_xor(acc.z, 16); acc.w += __shfl_xor(acc.w, 16);
    acc.x += __shfl_xor(acc.x, 32); acc.y += __shfl_xor(acc.y, 32);
    acc.z += __shfl_xor(acc.z, 32); acc.w += __shfl_xor(acc.w, 32);
    if (eg == 0) {
        float s = dinv[node];
        float4 bb = *(const float4*)&bias[f4];
        ushort4 o;
        o.x = f2bf(fmaxf(acc.x * s + bb.x, 0.f));
        o.y = f2bf(fmaxf(acc.y * s + bb.y, 0.f));
        o.z = f2bf(fmaxf(acc.z * s + bb.z, 0.f));
        o.w = f2bf(fmaxf(acc.w * s + bb.w, 0.f));
        *(ushort4*)&outp[(size_t)node * 64 + f4] = o;
    }
}

// ---------------- fused segmented mean-pool + MLP head (4-wave row-sum, bf16 in) -------------
__device__ __forceinline__ int lower_bound_dev(const int* __restrict__ a, int n, int v) {
    int lo = 0, hi = n;
    while (lo < hi) {
        int m = (lo + hi) >> 1;
        if (a[m] < v) lo = m + 1; else hi = m;
    }
    return lo;
}

__global__ __launch_bounds__(256) void pool_head_kernel(
    const unsigned short* __restrict__ h, const int* __restrict__ batch,
    const float* __restrict__ W1, const float* __restrict__ b1,
    const float* __restrict__ W2, const float* __restrict__ b2,
    float* __restrict__ out, int nNodes, int nGraphs) {
    __shared__ float psum[4][64];
    __shared__ float p[64];
    __shared__ float t64[64];
    int g = blockIdx.x;
    int tid = threadIdx.x;
    int f = tid & 63;
    int q = tid >> 6;  // wave id 0..3
    int lo = lower_bound_dev(batch, nNodes, g);
    int hi = lower_bound_dev(batch, nNodes, g + 1);
    float sum = 0.0f;
    for (int i = lo + q; i < hi; i += 4) sum += bf2f(h[(size_t)i * 64 + f]);
    psum[q][f] = sum;
    __syncthreads();
    if (tid < 64) {  // wave 0 only; intra-wave lockstep below
        float s = psum[0][f] + psum[1][f] + psum[2][f] + psum[3][f];
        float inv = 1.0f / fmaxf((float)(hi - lo), 1.0f);
        p[f] = s * inv;
        float acc = b1[f];
#pragma unroll
        for (int k = 0; k < 64; ++k) acc += p[k] * W1[k * 64 + f];
        t64[f] = fmaxf(acc, 0.0f);
        if (f < OUT_DIM) {
            float acc2 = b2[f];
#pragma unroll
            for (int k = 0; k < 64; ++k) acc2 += t64[k] * W2[k * OUT_DIM + f];
            out[g * OUT_DIM + f] = acc2;
        }
        if (g == 0 && f == 0) out[nGraphs * OUT_DIM] = 0.0f;  // trailing scalar output
    }
}

extern "C" void kernel_launch(void* const* d_in, const int* in_sizes, int n_in,
                              void* d_out, int out_size, void* d_ws, size_t ws_size,
                              hipStream_t stream) {
    const float* x      = (const float*)d_in[0];
    const int*   eidx   = (const int*)d_in[1];
    const int*   batch  = (const int*)d_in[2];
    const float* W1     = (const float*)d_in[3];
    const float* b1     = (const float*)d_in[4];
    const float* W2     = (const float*)d_in[5];
    const float* b2     = (const float*)d_in[6];
    const float* W3     = (const float*)d_in[7];
    const float* b3     = (const float*)d_in[8];
    const float* lin_W1 = (const float*)d_in[9];
    const float* lin_b1 = (const float*)d_in[10];
    const float* lin_W2 = (const float*)d_in[11];
    const float* lin_b2 = (const float*)d_in[12];
    float* out = (float*)d_out;

    const int E = in_sizes[1] / 2;
    const int N = N_NODES;
    const int NF = N * HID;
    const int epb = (E + NBLK - 1) / NBLK;

    const int* src = eidx;
    const int* dst = eidx + E;

    // workspace layout
    unsigned short* buf1 = (unsigned short*)d_ws;  // hs bf16 [N,64]
    unsigned short* buf2 = buf1 + NF;              // h  bf16 [N,64]
    float* dinv = (float*)(buf2 + NF);             // [N]
    int* bhist  = (int*)(dinv + N);                // [NBLK * NB_BUCK] (in-place counts->bases)
    int* bsum   = bhist + NBLK * NB_BUCK;          // [NB_BUCK]
    int* bstart = bsum + NB_BUCK;                  // [NB_BUCK+1]
    int* rs     = bstart + NB_BUCK + 1;            // [N+1]
    int* csr_src = rs + N + 1;                     // [E]
    unsigned* pairs = (unsigned*)(csr_src + E);    // [E]

    const int TILES = (N + 63) / 64;   // 782
    const int GBLK = (N + 3) / 4;      // 12500 (exact: 4*12500 = 50000)

    // ---- atomic-free edge build ----
    p1_hist_kernel<<<NBLK, BLDT, 0, stream>>>(dst, bhist, E, epb);
    scanA_kernel<<<NB_BUCK, NBLK, 0, stream>>>(bhist, bsum);
    bscan_kernel<<<1, 1024, 0, stream>>>(bsum, bstart, NB_BUCK, E);
    p2_place_kernel<<<NBLK, BLDT, 0, stream>>>(src, dst, bstart, bhist, pairs, E, epb);
    csr_scatter2_kernel<<<NB_BUCK, 256, 0, stream>>>(pairs, bstart, rs, dinv, csr_src, N);

    // ---- layer 1: x @ W1 -> hs1 ----
    linear1_kernel<<<TILES, 256, 0, stream>>>(x, W1, dinv, buf1, N);
    // ---- gather1 + linear2 fused: hs1 -> h1 -> hs2 ----
    gather_linear_kernel<<<GBLK, 256, 0, stream>>>(buf1, rs, csr_src, dinv, b1, W2, buf2, N);
    // ---- gather2 + linear3 fused: hs2 -> h2 -> hs3 ----
    gather_linear_kernel<<<GBLK, 256, 0, stream>>>(buf2, rs, csr_src, dinv, b2, W3, buf1, N);
    // ---- gather3: hs3 -> h3 ----
    gather_kernel<<<GBLK, 256, 0, stream>>>(buf1, rs, csr_src, dinv, b3, buf2, N);

    // ---- fused pool + head ----
    pool_head_kernel<<<N_GRAPHS, 256, 0, stream>>>(buf2, batch, lin_W1, lin_b1, lin_W2, lin_b2,
                                                   out, N, N_GRAPHS);
}

// Round 13
// 258.357 us; speedup vs baseline: 2.3713x; 2.3713x over previous
//
#include <hip/hip_runtime.h>
#include <hip/hip_bf16.h>

#define N_NODES 50000
#define N_EDGES 800000
#define N_GRAPHS 500
#define IN_DIM 128
#define HID 64
#define OUT_DIM 10
#define NB_BUCK ((N_NODES + 63) >> 6)  // 782 buckets of 64 nodes
#define NBLK 128                       // edge chunks (~6250 edges each)
#define BLDT 512                       // build-kernel block size

// ---- bf16 helpers: exact expand on load, RNE on store ----
__device__ __forceinline__ float bf2f(unsigned short u) {
    return __uint_as_float(((unsigned)u) << 16);
}
__device__ __forceinline__ unsigned short f2bf(float f) {
    unsigned x = __float_as_uint(f);
    x += 0x7fffu + ((x >> 16) & 1u);  // round-to-nearest-even
    return (unsigned short)(x >> 16);
}

// ---------------- P1: per-chunk bucket histogram (LDS, no global atomics) ----------------
__global__ __launch_bounds__(BLDT) void p1_hist_kernel(const int* __restrict__ dst,
                                                       int* __restrict__ bhist, int e, int epb) {
    __shared__ int h[NB_BUCK];
    int tid = threadIdx.x;
    int blk = blockIdx.x;
    for (int i = tid; i < NB_BUCK; i += BLDT) h[i] = 0;
    __syncthreads();
    int e0 = blk * epb;
    int e1 = e0 + epb;
    if (e1 > e) e1 = e;
    for (int i = e0 + tid; i < e1; i += BLDT) atomicAdd(&h[dst[i] >> 6], 1);
    __syncthreads();
    for (int i = tid; i < NB_BUCK; i += BLDT) bhist[blk * NB_BUCK + i] = h[i];
}

// ---- scanA: per bucket, scan NBLK chunk counts IN PLACE (bhist -> exclusive bases) + total ----
__global__ __launch_bounds__(NBLK) void scanA_kernel(int* __restrict__ bhist,
                                                     int* __restrict__ bsum) {
    __shared__ int s[NBLK];
    int b = blockIdx.x;
    int t = threadIdx.x;  // NBLK threads
    int c = bhist[t * NB_BUCK + b];
    s[t] = c;
    __syncthreads();
    for (int off = 1; off < NBLK; off <<= 1) {
        int x = (t >= off) ? s[t - off] : 0;
        __syncthreads();
        s[t] += x;
        __syncthreads();
    }
    bhist[t * NB_BUCK + b] = s[t] - c;  // in-place: exclusive prefix for chunk t
    if (t == NBLK - 1) bsum[b] = s[t];
}

// ---------------- bscan: exclusive scan over bucket totals ----------------
__global__ __launch_bounds__(1024) void bscan_kernel(const int* __restrict__ bsum,
                                                     int* __restrict__ bstart, int nb, int e) {
    __shared__ int s[1024];
    int t = threadIdx.x;
    int v = (t < nb) ? bsum[t] : 0;
    s[t] = v;
    __syncthreads();
    for (int off = 1; off < 1024; off <<= 1) {
        int x = (t >= off) ? s[t - off] : 0;
        __syncthreads();
        s[t] += x;
        __syncthreads();
    }
    if (t < nb) bstart[t] = s[t] - v;
    if (t == 0) bstart[nb] = e;
}

// ---------------- P2: place edges into bucket-grouped pairs (block-local dense segments) ------
__global__ __launch_bounds__(BLDT) void p2_place_kernel(
    const int* __restrict__ src, const int* __restrict__ dst, const int* __restrict__ bstart,
    const int* __restrict__ base, unsigned* __restrict__ pairs, int e, int epb) {
    __shared__ int h[NB_BUCK];   // local rank counters
    __shared__ int sb[NB_BUCK];  // global segment base for this chunk
    int tid = threadIdx.x;
    int blk = blockIdx.x;
    for (int i = tid; i < NB_BUCK; i += BLDT) {
        h[i] = 0;
        sb[i] = bstart[i] + base[blk * NB_BUCK + i];
    }
    __syncthreads();
    int e0 = blk * epb;
    int e1 = e0 + epb;
    if (e1 > e) e1 = e;
    for (int i = e0 + tid; i < e1; i += BLDT) {
        int d = dst[i];
        int b = d >> 6;
        int r = atomicAdd(&h[b], 1);
        pairs[sb[b] + r] = ((unsigned)(d & 63) << 16) | (unsigned)src[i];
    }
}

// ---------------- csr_scatter2: per bucket -> rs, dinv, csr_src (no global atomics) ----------
__global__ __launch_bounds__(256) void csr_scatter2_kernel(
    const unsigned* __restrict__ pairs, const int* __restrict__ bstart,
    int* __restrict__ rs, float* __restrict__ dinv, int* __restrict__ csr_src, int n) {
    __shared__ int lcnt[64];
    __shared__ int lcur[64];
    int b = blockIdx.x;
    int tid = threadIdx.x;
    int beg = bstart[b], end = bstart[b + 1];
    if (tid < 64) lcnt[tid] = 0;
    __syncthreads();
    for (int i = beg + tid; i < end; i += 256) atomicAdd(&lcnt[pairs[i] >> 16], 1);
    __syncthreads();
    if (tid < 64) {  // wave 0: scan the 64 node counts
        int c = lcnt[tid];
        int v = c;
#pragma unroll
        for (int off = 1; off < 64; off <<= 1) {
            int t = __shfl_up(v, off);
            if (tid >= off) v += t;
        }
        int excl = v - c;
        int node = b * 64 + tid;
        if (node <= n) {
            rs[node] = beg + excl;  // node==n lands on rs[N]=E (last bucket's tail)
            if (node < n) dinv[node] = rsqrtf((float)(c + 1));
        }
        lcur[tid] = beg + excl;
    }
    __syncthreads();
    for (int i = beg + tid; i < end; i += 256) {
        unsigned p = pairs[i];
        int slot = atomicAdd(&lcur[p >> 16], 1);
        csr_src[slot] = (int)(p & 0xffffu);
    }
}

// ---------------- layer-1 linear: fp32 A (K=128) -> bf16 hs (+ dinv pre-scale) ----------------
__global__ __launch_bounds__(256) void linear1_kernel(
    const float* __restrict__ A, const float* __restrict__ W,
    const float* __restrict__ dinv, unsigned short* __restrict__ C, int n) {
    const int K = IN_DIM;
    __shared__ float As[64][K + 4];
    __shared__ float Ws[K][64];
    int tid = threadIdx.x;
    int tx = tid & 15;
    int ty = tid >> 4;
    int block0 = blockIdx.x * 64;
    int rows = n - block0;
    if (rows > 64) rows = 64;

    const float* Abase = A + (size_t)block0 * K;
    int totalA4 = (rows * K) >> 2;
    for (int i4 = tid; i4 < totalA4; i4 += 256) {
        int i = i4 << 2;
        float4 v = *(const float4*)(Abase + i);
        *(float4*)&As[i / K][i % K] = v;
    }
    {
        const float4* Wv = (const float4*)W;
        float4* Wsv = (float4*)&Ws[0][0];
        for (int i = tid; i < K * 16; i += 256) Wsv[i] = Wv[i];
    }
    __syncthreads();

    float acc[4][4] = {};
#pragma unroll 2
    for (int k = 0; k < K; k += 4) {
        float4 a[4];
#pragma unroll
        for (int i = 0; i < 4; ++i) a[i] = *(const float4*)&As[ty * 4 + i][k];
        float4 w[4];
#pragma unroll
        for (int kk = 0; kk < 4; ++kk) w[kk] = *(const float4*)&Ws[k + kk][tx * 4];
#pragma unroll
        for (int i = 0; i < 4; ++i) {
            float av[4] = {a[i].x, a[i].y, a[i].z, a[i].w};
#pragma unroll
            for (int kk = 0; kk < 4; ++kk) {
                acc[i][0] += av[kk] * w[kk].x;
                acc[i][1] += av[kk] * w[kk].y;
                acc[i][2] += av[kk] * w[kk].z;
                acc[i][3] += av[kk] * w[kk].w;
            }
        }
    }

#pragma unroll
    for (int i = 0; i < 4; ++i) {
        int r = ty * 4 + i;
        if (r < rows) {
            float s = dinv[block0 + r];
            ushort4 v;
            v.x = f2bf(acc[i][0] * s);
            v.y = f2bf(acc[i][1] * s);
            v.z = f2bf(acc[i][2] * s);
            v.w = f2bf(acc[i][3] * s);
            *(ushort4*)&C[(size_t)(block0 + r) * 64 + tx * 4] = v;
        }
    }
}

// ---------------- layers-2/3 linear: bf16 A (K=64) -> bf16 hs (+ dinv pre-scale) --------------
__global__ __launch_bounds__(256) void linear_bf_kernel(
    const unsigned short* __restrict__ A, const float* __restrict__ W,
    const float* __restrict__ dinv, unsigned short* __restrict__ C, int n) {
    const int K = HID;
    __shared__ float As[64][K + 4];
    __shared__ float Ws[K][64];
    int tid = threadIdx.x;
    int tx = tid & 15;
    int ty = tid >> 4;
    int block0 = blockIdx.x * 64;
    int rows = n - block0;
    if (rows > 64) rows = 64;

    const unsigned short* Abase = A + (size_t)block0 * K;
    int total8 = rows * 8;  // 16B (8 bf16) units
    for (int u = tid; u < total8; u += 256) {
        int r = u >> 3;
        int c8 = (u & 7) << 3;
        uint4 raw = *(const uint4*)(Abase + (size_t)r * K + c8);
        float4 a0, a1;
        a0.x = __uint_as_float(raw.x << 16);
        a0.y = __uint_as_float(raw.x & 0xffff0000u);
        a0.z = __uint_as_float(raw.y << 16);
        a0.w = __uint_as_float(raw.y & 0xffff0000u);
        a1.x = __uint_as_float(raw.z << 16);
        a1.y = __uint_as_float(raw.z & 0xffff0000u);
        a1.z = __uint_as_float(raw.w << 16);
        a1.w = __uint_as_float(raw.w & 0xffff0000u);
        *(float4*)&As[r][c8] = a0;
        *(float4*)&As[r][c8 + 4] = a1;
    }
    {
        const float4* Wv = (const float4*)W;
        float4* Wsv = (float4*)&Ws[0][0];
        for (int i = tid; i < K * 16; i += 256) Wsv[i] = Wv[i];
    }
    __syncthreads();

    float acc[4][4] = {};
#pragma unroll 2
    for (int k = 0; k < K; k += 4) {
        float4 a[4];
#pragma unroll
        for (int i = 0; i < 4; ++i) a[i] = *(const float4*)&As[ty * 4 + i][k];
        float4 w[4];
#pragma unroll
        for (int kk = 0; kk < 4; ++kk) w[kk] = *(const float4*)&Ws[k + kk][tx * 4];
#pragma unroll
        for (int i = 0; i < 4; ++i) {
            float av[4] = {a[i].x, a[i].y, a[i].z, a[i].w};
#pragma unroll
            for (int kk = 0; kk < 4; ++kk) {
                acc[i][0] += av[kk] * w[kk].x;
                acc[i][1] += av[kk] * w[kk].y;
                acc[i][2] += av[kk] * w[kk].z;
                acc[i][3] += av[kk] * w[kk].w;
            }
        }
    }

#pragma unroll
    for (int i = 0; i < 4; ++i) {
        int r = ty * 4 + i;
        if (r < rows) {
            float s = dinv[block0 + r];
            ushort4 v;
            v.x = f2bf(acc[i][0] * s);
            v.y = f2bf(acc[i][1] * s);
            v.z = f2bf(acc[i][2] * s);
            v.w = f2bf(acc[i][3] * s);
            *(ushort4*)&C[(size_t)(block0 + r) * 64 + tx * 4] = v;
        }
    }
}

// ------- per-node bf16 gather: contiguous per-group quarters, 4/2/1 batch ladder -------------
__global__ __launch_bounds__(256) void gather_kernel(
    const unsigned short* __restrict__ hs, const int* __restrict__ rs,
    const int* __restrict__ csr_src, const float* __restrict__ dinv,
    const float* __restrict__ bias, unsigned short* __restrict__ outp, int n) {
    int wave = threadIdx.x >> 6;
    int node = blockIdx.x * 4 + wave;
    if (node >= n) return;
    int lane = threadIdx.x & 63;
    int eg = lane >> 4;         // edge group 0..3
    int f4 = (lane & 15) << 2;  // feature quad
    int beg = rs[node], end = rs[node + 1];
    int len = end - beg;
    int q = (len + 3) >> 2;     // per-group quota (contiguous quarter)
    int mb = beg + eg * q;
    int me = mb + q;
    if (me > end) me = end;
    float4 acc = {0.f, 0.f, 0.f, 0.f};
    if (eg == 0) {  // self-loop (pre-scaled)
        ushort4 u = *(const ushort4*)&hs[(size_t)node * 64 + f4];
        acc.x = bf2f(u.x); acc.y = bf2f(u.y); acc.z = bf2f(u.z); acc.w = bf2f(u.w);
    }
    int j = mb;
    for (; j + 3 < me; j += 4) {  // 4 rows in flight
        int s0 = csr_src[j];
        int s1 = csr_src[j + 1];
        int s2 = csr_src[j + 2];
        int s3 = csr_src[j + 3];
        ushort4 u0 = *(const ushort4*)&hs[(size_t)s0 * 64 + f4];
        ushort4 u1 = *(const ushort4*)&hs[(size_t)s1 * 64 + f4];
        ushort4 u2 = *(const ushort4*)&hs[(size_t)s2 * 64 + f4];
        ushort4 u3 = *(const ushort4*)&hs[(size_t)s3 * 64 + f4];
        acc.x += bf2f(u0.x) + bf2f(u1.x) + bf2f(u2.x) + bf2f(u3.x);
        acc.y += bf2f(u0.y) + bf2f(u1.y) + bf2f(u2.y) + bf2f(u3.y);
        acc.z += bf2f(u0.z) + bf2f(u1.z) + bf2f(u2.z) + bf2f(u3.z);
        acc.w += bf2f(u0.w) + bf2f(u1.w) + bf2f(u2.w) + bf2f(u3.w);
    }
    if (j + 1 < me) {  // 2 rows in flight
        int s0 = csr_src[j];
        int s1 = csr_src[j + 1];
        ushort4 u0 = *(const ushort4*)&hs[(size_t)s0 * 64 + f4];
        ushort4 u1 = *(const ushort4*)&hs[(size_t)s1 * 64 + f4];
        acc.x += bf2f(u0.x) + bf2f(u1.x);
        acc.y += bf2f(u0.y) + bf2f(u1.y);
        acc.z += bf2f(u0.z) + bf2f(u1.z);
        acc.w += bf2f(u0.w) + bf2f(u1.w);
        j += 2;
    }
    if (j < me) {
        int s = csr_src[j];
        ushort4 u = *(const ushort4*)&hs[(size_t)s * 64 + f4];
        acc.x += bf2f(u.x); acc.y += bf2f(u.y); acc.z += bf2f(u.z); acc.w += bf2f(u.w);
    }
    // merge the 4 edge groups: butterfly over lane bits 4,5
    acc.x += __shfl_xor(acc.x, 16); acc.y += __shfl_xor(acc.y, 16);
    acc.z += __shfl_xor(acc.z, 16); acc.w += __shfl_xor(acc.w, 16);
    acc.x += __shfl_xor(acc.x, 32); acc.y += __shfl_xor(acc.y, 32);
    acc.z += __shfl_xor(acc.z, 32); acc.w += __shfl_xor(acc.w, 32);
    if (eg == 0) {
        float s = dinv[node];
        float4 bb = *(const float4*)&bias[f4];
        ushort4 o;
        o.x = f2bf(fmaxf(acc.x * s + bb.x, 0.f));
        o.y = f2bf(fmaxf(acc.y * s + bb.y, 0.f));
        o.z = f2bf(fmaxf(acc.z * s + bb.z, 0.f));
        o.w = f2bf(fmaxf(acc.w * s + bb.w, 0.f));
        *(ushort4*)&outp[(size_t)node * 64 + f4] = o;
    }
}

// ---------------- fused segmented mean-pool + MLP head (4-wave row-sum, bf16 in) -------------
__device__ __forceinline__ int lower_bound_dev(const int* __restrict__ a, int n, int v) {
    int lo = 0, hi = n;
    while (lo < hi) {
        int m = (lo + hi) >> 1;
        if (a[m] < v) lo = m + 1; else hi = m;
    }
    return lo;
}

__global__ __launch_bounds__(256) void pool_head_kernel(
    const unsigned short* __restrict__ h, const int* __restrict__ batch,
    const float* __restrict__ W1, const float* __restrict__ b1,
    const float* __restrict__ W2, const float* __restrict__ b2,
    float* __restrict__ out, int nNodes, int nGraphs) {
    __shared__ float psum[4][64];
    __shared__ float p[64];
    __shared__ float t64[64];
    int g = blockIdx.x;
    int tid = threadIdx.x;
    int f = tid & 63;
    int q = tid >> 6;  // wave id 0..3
    int lo = lower_bound_dev(batch, nNodes, g);
    int hi = lower_bound_dev(batch, nNodes, g + 1);
    float sum = 0.0f;
    for (int i = lo + q; i < hi; i += 4) sum += bf2f(h[(size_t)i * 64 + f]);
    psum[q][f] = sum;
    __syncthreads();
    if (tid < 64) {  // wave 0 only; intra-wave lockstep below
        float s = psum[0][f] + psum[1][f] + psum[2][f] + psum[3][f];
        float inv = 1.0f / fmaxf((float)(hi - lo), 1.0f);
        p[f] = s * inv;
        float acc = b1[f];
#pragma unroll
        for (int k = 0; k < 64; ++k) acc += p[k] * W1[k * 64 + f];
        t64[f] = fmaxf(acc, 0.0f);
        if (f < OUT_DIM) {
            float acc2 = b2[f];
#pragma unroll
            for (int k = 0; k < 64; ++k) acc2 += t64[k] * W2[k * OUT_DIM + f];
            out[g * OUT_DIM + f] = acc2;
        }
        if (g == 0 && f == 0) out[nGraphs * OUT_DIM] = 0.0f;  // trailing scalar output
    }
}

extern "C" void kernel_launch(void* const* d_in, const int* in_sizes, int n_in,
                              void* d_out, int out_size, void* d_ws, size_t ws_size,
                              hipStream_t stream) {
    const float* x      = (const float*)d_in[0];
    const int*   eidx   = (const int*)d_in[1];
    const int*   batch  = (const int*)d_in[2];
    const float* W1     = (const float*)d_in[3];
    const float* b1     = (const float*)d_in[4];
    const float* W2     = (const float*)d_in[5];
    const float* b2     = (const float*)d_in[6];
    const float* W3     = (const float*)d_in[7];
    const float* b3     = (const float*)d_in[8];
    const float* lin_W1 = (const float*)d_in[9];
    const float* lin_b1 = (const float*)d_in[10];
    const float* lin_W2 = (const float*)d_in[11];
    const float* lin_b2 = (const float*)d_in[12];
    float* out = (float*)d_out;

    const int E = in_sizes[1] / 2;
    const int N = N_NODES;
    const int NF = N * HID;
    const int epb = (E + NBLK - 1) / NBLK;

    const int* src = eidx;
    const int* dst = eidx + E;

    // workspace layout
    unsigned short* buf1 = (unsigned short*)d_ws;  // hs bf16 [N,64]
    unsigned short* buf2 = buf1 + NF;              // h  bf16 [N,64]
    float* dinv = (float*)(buf2 + NF);             // [N]
    int* bhist  = (int*)(dinv + N);                // [NBLK * NB_BUCK] (in-place counts->bases)
    int* bsum   = bhist + NBLK * NB_BUCK;          // [NB_BUCK]
    int* bstart = bsum + NB_BUCK;                  // [NB_BUCK+1]
    int* rs     = bstart + NB_BUCK + 1;            // [N+1]
    int* csr_src = rs + N + 1;                     // [E]
    unsigned* pairs = (unsigned*)(csr_src + E);    // [E]

    const int TILES = (N + 63) / 64;  // 782
    const int GBLK = (N + 3) / 4;     // 12500

    // ---- atomic-free edge build ----
    p1_hist_kernel<<<NBLK, BLDT, 0, stream>>>(dst, bhist, E, epb);
    scanA_kernel<<<NB_BUCK, NBLK, 0, stream>>>(bhist, bsum);
    bscan_kernel<<<1, 1024, 0, stream>>>(bsum, bstart, NB_BUCK, E);
    p2_place_kernel<<<NBLK, BLDT, 0, stream>>>(src, dst, bstart, bhist, pairs, E, epb);
    csr_scatter2_kernel<<<NB_BUCK, 256, 0, stream>>>(pairs, bstart, rs, dinv, csr_src, N);

    // ---- layer 1 ----
    linear1_kernel<<<TILES, 256, 0, stream>>>(x, W1, dinv, buf1, N);
    gather_kernel<<<GBLK, 256, 0, stream>>>(buf1, rs, csr_src, dinv, b1, buf2, N);

    // ---- layer 2 ----
    linear_bf_kernel<<<TILES, 256, 0, stream>>>(buf2, W2, dinv, buf1, N);
    gather_kernel<<<GBLK, 256, 0, stream>>>(buf1, rs, csr_src, dinv, b2, buf2, N);

    // ---- layer 3 ----
    linear_bf_kernel<<<TILES, 256, 0, stream>>>(buf2, W3, dinv, buf1, N);
    gather_kernel<<<GBLK, 256, 0, stream>>>(buf1, rs, csr_src, dinv, b3, buf2, N);

    // ---- fused pool + head ----
    pool_head_kernel<<<N_GRAPHS, 256, 0, stream>>>(buf2, batch, lin_W1, lin_b1, lin_W2, lin_b2,
                                                   out, N, N_GRAPHS);
}

// Round 14
// 257.586 us; speedup vs baseline: 2.3784x; 1.0030x over previous
//
#include <hip/hip_runtime.h>
#include <hip/hip_bf16.h>

#define N_NODES 50000
#define N_EDGES 800000
#define N_GRAPHS 500
#define IN_DIM 128
#define HID 64
#define OUT_DIM 10
#define NB_BUCK ((N_NODES + 63) >> 6)  // 782 buckets of 64 nodes
#define NBLK 256                       // edge chunks (~3128 edges each) -> 1 block/CU
#define BLDT 256                       // build-kernel block size

// ---- bf16 helpers: exact expand on load, RNE on store ----
__device__ __forceinline__ float bf2f(unsigned short u) {
    return __uint_as_float(((unsigned)u) << 16);
}
__device__ __forceinline__ unsigned short f2bf(float f) {
    unsigned x = __float_as_uint(f);
    x += 0x7fffu + ((x >> 16) & 1u);  // round-to-nearest-even
    return (unsigned short)(x >> 16);
}

// ---------------- P1: per-chunk bucket histogram (LDS, int4 edge reads) ----------------
__global__ __launch_bounds__(BLDT) void p1_hist_kernel(const int* __restrict__ dst,
                                                       int* __restrict__ bhist, int e, int epb) {
    __shared__ int h[NB_BUCK];
    int tid = threadIdx.x;
    int blk = blockIdx.x;
    for (int i = tid; i < NB_BUCK; i += BLDT) h[i] = 0;
    __syncthreads();
    int e0 = blk * epb;
    int e1 = e0 + epb;
    if (e1 > e) e1 = e;
    int i = e0 + tid * 4;
    for (; i + 3 < e1; i += BLDT * 4) {
        int4 d4 = *(const int4*)&dst[i];
        atomicAdd(&h[d4.x >> 6], 1);
        atomicAdd(&h[d4.y >> 6], 1);
        atomicAdd(&h[d4.z >> 6], 1);
        atomicAdd(&h[d4.w >> 6], 1);
    }
    for (int k = i; k < e1 && k < i + 4; ++k) atomicAdd(&h[dst[k] >> 6], 1);
    __syncthreads();
    for (int j = tid; j < NB_BUCK; j += BLDT) bhist[blk * NB_BUCK + j] = h[j];
}

// ---- scanA: per bucket, scan NBLK chunk counts IN PLACE (bhist -> exclusive bases) + total ----
__global__ __launch_bounds__(NBLK) void scanA_kernel(int* __restrict__ bhist,
                                                     int* __restrict__ bsum) {
    __shared__ int s[NBLK];
    int b = blockIdx.x;
    int t = threadIdx.x;  // NBLK threads
    int c = bhist[t * NB_BUCK + b];
    s[t] = c;
    __syncthreads();
    for (int off = 1; off < NBLK; off <<= 1) {
        int x = (t >= off) ? s[t - off] : 0;
        __syncthreads();
        s[t] += x;
        __syncthreads();
    }
    bhist[t * NB_BUCK + b] = s[t] - c;  // in-place: exclusive prefix for chunk t
    if (t == NBLK - 1) bsum[b] = s[t];
}

// ---------------- bscan: exclusive scan over bucket totals ----------------
__global__ __launch_bounds__(1024) void bscan_kernel(const int* __restrict__ bsum,
                                                     int* __restrict__ bstart, int nb, int e) {
    __shared__ int s[1024];
    int t = threadIdx.x;
    int v = (t < nb) ? bsum[t] : 0;
    s[t] = v;
    __syncthreads();
    for (int off = 1; off < 1024; off <<= 1) {
        int x = (t >= off) ? s[t - off] : 0;
        __syncthreads();
        s[t] += x;
        __syncthreads();
    }
    if (t < nb) bstart[t] = s[t] - v;
    if (t == 0) bstart[nb] = e;
}

// ---------------- P2: place edges into bucket-grouped pairs (int4 edge reads) ------
__global__ __launch_bounds__(BLDT) void p2_place_kernel(
    const int* __restrict__ src, const int* __restrict__ dst, const int* __restrict__ bstart,
    const int* __restrict__ base, unsigned* __restrict__ pairs, int e, int epb) {
    __shared__ int h[NB_BUCK];   // local rank counters
    __shared__ int sb[NB_BUCK];  // global segment base for this chunk
    int tid = threadIdx.x;
    int blk = blockIdx.x;
    for (int i = tid; i < NB_BUCK; i += BLDT) {
        h[i] = 0;
        sb[i] = bstart[i] + base[blk * NB_BUCK + i];
    }
    __syncthreads();
    int e0 = blk * epb;
    int e1 = e0 + epb;
    if (e1 > e) e1 = e;
    int i = e0 + tid * 4;
    for (; i + 3 < e1; i += BLDT * 4) {
        int4 d4 = *(const int4*)&dst[i];
        int4 s4 = *(const int4*)&src[i];
        int b0 = d4.x >> 6, b1 = d4.y >> 6, b2 = d4.z >> 6, b3 = d4.w >> 6;
        int r0 = atomicAdd(&h[b0], 1);
        int r1 = atomicAdd(&h[b1], 1);
        int r2 = atomicAdd(&h[b2], 1);
        int r3 = atomicAdd(&h[b3], 1);
        pairs[sb[b0] + r0] = ((unsigned)(d4.x & 63) << 16) | (unsigned)s4.x;
        pairs[sb[b1] + r1] = ((unsigned)(d4.y & 63) << 16) | (unsigned)s4.y;
        pairs[sb[b2] + r2] = ((unsigned)(d4.z & 63) << 16) | (unsigned)s4.z;
        pairs[sb[b3] + r3] = ((unsigned)(d4.w & 63) << 16) | (unsigned)s4.w;
    }
    for (int k = i; k < e1 && k < i + 4; ++k) {
        int d = dst[k];
        int b = d >> 6;
        int r = atomicAdd(&h[b], 1);
        pairs[sb[b] + r] = ((unsigned)(d & 63) << 16) | (unsigned)src[k];
    }
}

// ---------------- csr_scatter2: per bucket -> rs, dinv, csr_src (no global atomics) ----------
__global__ __launch_bounds__(256) void csr_scatter2_kernel(
    const unsigned* __restrict__ pairs, const int* __restrict__ bstart,
    int* __restrict__ rs, float* __restrict__ dinv, int* __restrict__ csr_src, int n) {
    __shared__ int lcnt[64];
    __shared__ int lcur[64];
    int b = blockIdx.x;
    int tid = threadIdx.x;
    int beg = bstart[b], end = bstart[b + 1];
    if (tid < 64) lcnt[tid] = 0;
    __syncthreads();
    for (int i = beg + tid; i < end; i += 256) atomicAdd(&lcnt[pairs[i] >> 16], 1);
    __syncthreads();
    if (tid < 64) {  // wave 0: scan the 64 node counts
        int c = lcnt[tid];
        int v = c;
#pragma unroll
        for (int off = 1; off < 64; off <<= 1) {
            int t = __shfl_up(v, off);
            if (tid >= off) v += t;
        }
        int excl = v - c;
        int node = b * 64 + tid;
        if (node <= n) {
            rs[node] = beg + excl;  // node==n lands on rs[N]=E (last bucket's tail)
            if (node < n) dinv[node] = rsqrtf((float)(c + 1));
        }
        lcur[tid] = beg + excl;
    }
    __syncthreads();
    for (int i = beg + tid; i < end; i += 256) {
        unsigned p = pairs[i];
        int slot = atomicAdd(&lcur[p >> 16], 1);
        csr_src[slot] = (int)(p & 0xffffu);
    }
}

// ---------------- layer-1 linear: fp32 A (K=128) -> bf16 hs (+ dinv pre-scale) ----------------
__global__ __launch_bounds__(256) void linear1_kernel(
    const float* __restrict__ A, const float* __restrict__ W,
    const float* __restrict__ dinv, unsigned short* __restrict__ C, int n) {
    const int K = IN_DIM;
    __shared__ float As[64][K + 4];
    __shared__ float Ws[K][64];
    int tid = threadIdx.x;
    int tx = tid & 15;
    int ty = tid >> 4;
    int block0 = blockIdx.x * 64;
    int rows = n - block0;
    if (rows > 64) rows = 64;

    const float* Abase = A + (size_t)block0 * K;
    int totalA4 = (rows * K) >> 2;
    for (int i4 = tid; i4 < totalA4; i4 += 256) {
        int i = i4 << 2;
        float4 v = *(const float4*)(Abase + i);
        *(float4*)&As[i / K][i % K] = v;
    }
    {
        const float4* Wv = (const float4*)W;
        float4* Wsv = (float4*)&Ws[0][0];
        for (int i = tid; i < K * 16; i += 256) Wsv[i] = Wv[i];
    }
    __syncthreads();

    float acc[4][4] = {};
#pragma unroll 2
    for (int k = 0; k < K; k += 4) {
        float4 a[4];
#pragma unroll
        for (int i = 0; i < 4; ++i) a[i] = *(const float4*)&As[ty * 4 + i][k];
        float4 w[4];
#pragma unroll
        for (int kk = 0; kk < 4; ++kk) w[kk] = *(const float4*)&Ws[k + kk][tx * 4];
#pragma unroll
        for (int i = 0; i < 4; ++i) {
            float av[4] = {a[i].x, a[i].y, a[i].z, a[i].w};
#pragma unroll
            for (int kk = 0; kk < 4; ++kk) {
                acc[i][0] += av[kk] * w[kk].x;
                acc[i][1] += av[kk] * w[kk].y;
                acc[i][2] += av[kk] * w[kk].z;
                acc[i][3] += av[kk] * w[kk].w;
            }
        }
    }

#pragma unroll
    for (int i = 0; i < 4; ++i) {
        int r = ty * 4 + i;
        if (r < rows) {
            float s = dinv[block0 + r];
            ushort4 v;
            v.x = f2bf(acc[i][0] * s);
            v.y = f2bf(acc[i][1] * s);
            v.z = f2bf(acc[i][2] * s);
            v.w = f2bf(acc[i][3] * s);
            *(ushort4*)&C[(size_t)(block0 + r) * 64 + tx * 4] = v;
        }
    }
}

// ---------------- layers-2/3 linear: bf16 A (K=64) -> bf16 hs (+ dinv pre-scale) --------------
__global__ __launch_bounds__(256) void linear_bf_kernel(
    const unsigned short* __restrict__ A, const float* __restrict__ W,
    const float* __restrict__ dinv, unsigned short* __restrict__ C, int n) {
    const int K = HID;
    __shared__ float As[64][K + 4];
    __shared__ float Ws[K][64];
    int tid = threadIdx.x;
    int tx = tid & 15;
    int ty = tid >> 4;
    int block0 = blockIdx.x * 64;
    int rows = n - block0;
    if (rows > 64) rows = 64;

    const unsigned short* Abase = A + (size_t)block0 * K;
    int total8 = rows * 8;  // 16B (8 bf16) units
    for (int u = tid; u < total8; u += 256) {
        int r = u >> 3;
        int c8 = (u & 7) << 3;
        uint4 raw = *(const uint4*)(Abase + (size_t)r * K + c8);
        float4 a0, a1;
        a0.x = __uint_as_float(raw.x << 16);
        a0.y = __uint_as_float(raw.x & 0xffff0000u);
        a0.z = __uint_as_float(raw.y << 16);
        a0.w = __uint_as_float(raw.y & 0xffff0000u);
        a1.x = __uint_as_float(raw.z << 16);
        a1.y = __uint_as_float(raw.z & 0xffff0000u);
        a1.z = __uint_as_float(raw.w << 16);
        a1.w = __uint_as_float(raw.w & 0xffff0000u);
        *(float4*)&As[r][c8] = a0;
        *(float4*)&As[r][c8 + 4] = a1;
    }
    {
        const float4* Wv = (const float4*)W;
        float4* Wsv = (float4*)&Ws[0][0];
        for (int i = tid; i < K * 16; i += 256) Wsv[i] = Wv[i];
    }
    __syncthreads();

    float acc[4][4] = {};
#pragma unroll 2
    for (int k = 0; k < K; k += 4) {
        float4 a[4];
#pragma unroll
        for (int i = 0; i < 4; ++i) a[i] = *(const float4*)&As[ty * 4 + i][k];
        float4 w[4];
#pragma unroll
        for (int kk = 0; kk < 4; ++kk) w[kk] = *(const float4*)&Ws[k + kk][tx * 4];
#pragma unroll
        for (int i = 0; i < 4; ++i) {
            float av[4] = {a[i].x, a[i].y, a[i].z, a[i].w};
#pragma unroll
            for (int kk = 0; kk < 4; ++kk) {
                acc[i][0] += av[kk] * w[kk].x;
                acc[i][1] += av[kk] * w[kk].y;
                acc[i][2] += av[kk] * w[kk].z;
                acc[i][3] += av[kk] * w[kk].w;
            }
        }
    }

#pragma unroll
    for (int i = 0; i < 4; ++i) {
        int r = ty * 4 + i;
        if (r < rows) {
            float s = dinv[block0 + r];
            ushort4 v;
            v.x = f2bf(acc[i][0] * s);
            v.y = f2bf(acc[i][1] * s);
            v.z = f2bf(acc[i][2] * s);
            v.w = f2bf(acc[i][3] * s);
            *(ushort4*)&C[(size_t)(block0 + r) * 64 + tx * 4] = v;
        }
    }
}

// ------- per-node bf16 gather: contiguous per-group quarters, 4/2/1 batch ladder -------------
__global__ __launch_bounds__(256) void gather_kernel(
    const unsigned short* __restrict__ hs, const int* __restrict__ rs,
    const int* __restrict__ csr_src, const float* __restrict__ dinv,
    const float* __restrict__ bias, unsigned short* __restrict__ outp, int n) {
    int wave = threadIdx.x >> 6;
    int node = blockIdx.x * 4 + wave;
    if (node >= n) return;
    int lane = threadIdx.x & 63;
    int eg = lane >> 4;         // edge group 0..3
    int f4 = (lane & 15) << 2;  // feature quad
    int beg = rs[node], end = rs[node + 1];
    int len = end - beg;
    int q = (len + 3) >> 2;     // per-group quota (contiguous quarter)
    int mb = beg + eg * q;
    int me = mb + q;
    if (me > end) me = end;
    float4 acc = {0.f, 0.f, 0.f, 0.f};
    if (eg == 0) {  // self-loop (pre-scaled)
        ushort4 u = *(const ushort4*)&hs[(size_t)node * 64 + f4];
        acc.x = bf2f(u.x); acc.y = bf2f(u.y); acc.z = bf2f(u.z); acc.w = bf2f(u.w);
    }
    int j = mb;
    for (; j + 3 < me; j += 4) {  // 4 rows in flight
        int s0 = csr_src[j];
        int s1 = csr_src[j + 1];
        int s2 = csr_src[j + 2];
        int s3 = csr_src[j + 3];
        ushort4 u0 = *(const ushort4*)&hs[(size_t)s0 * 64 + f4];
        ushort4 u1 = *(const ushort4*)&hs[(size_t)s1 * 64 + f4];
        ushort4 u2 = *(const ushort4*)&hs[(size_t)s2 * 64 + f4];
        ushort4 u3 = *(const ushort4*)&hs[(size_t)s3 * 64 + f4];
        acc.x += bf2f(u0.x) + bf2f(u1.x) + bf2f(u2.x) + bf2f(u3.x);
        acc.y += bf2f(u0.y) + bf2f(u1.y) + bf2f(u2.y) + bf2f(u3.y);
        acc.z += bf2f(u0.z) + bf2f(u1.z) + bf2f(u2.z) + bf2f(u3.z);
        acc.w += bf2f(u0.w) + bf2f(u1.w) + bf2f(u2.w) + bf2f(u3.w);
    }
    if (j + 1 < me) {  // 2 rows in flight
        int s0 = csr_src[j];
        int s1 = csr_src[j + 1];
        ushort4 u0 = *(const ushort4*)&hs[(size_t)s0 * 64 + f4];
        ushort4 u1 = *(const ushort4*)&hs[(size_t)s1 * 64 + f4];
        acc.x += bf2f(u0.x) + bf2f(u1.x);
        acc.y += bf2f(u0.y) + bf2f(u1.y);
        acc.z += bf2f(u0.z) + bf2f(u1.z);
        acc.w += bf2f(u0.w) + bf2f(u1.w);
        j += 2;
    }
    if (j < me) {
        int s = csr_src[j];
        ushort4 u = *(const ushort4*)&hs[(size_t)s * 64 + f4];
        acc.x += bf2f(u.x); acc.y += bf2f(u.y); acc.z += bf2f(u.z); acc.w += bf2f(u.w);
    }
    // merge the 4 edge groups: butterfly over lane bits 4,5
    acc.x += __shfl_xor(acc.x, 16); acc.y += __shfl_xor(acc.y, 16);
    acc.z += __shfl_xor(acc.z, 16); acc.w += __shfl_xor(acc.w, 16);
    acc.x += __shfl_xor(acc.x, 32); acc.y += __shfl_xor(acc.y, 32);
    acc.z += __shfl_xor(acc.z, 32); acc.w += __shfl_xor(acc.w, 32);
    if (eg == 0) {
        float s = dinv[node];
        float4 bb = *(const float4*)&bias[f4];
        ushort4 o;
        o.x = f2bf(fmaxf(acc.x * s + bb.x, 0.f));
        o.y = f2bf(fmaxf(acc.y * s + bb.y, 0.f));
        o.z = f2bf(fmaxf(acc.z * s + bb.z, 0.f));
        o.w = f2bf(fmaxf(acc.w * s + bb.w, 0.f));
        *(ushort4*)&outp[(size_t)node * 64 + f4] = o;
    }
}

// ---------------- fused segmented mean-pool + MLP head (4-wave row-sum, bf16 in) -------------
__device__ __forceinline__ int lower_bound_dev(const int* __restrict__ a, int n, int v) {
    int lo = 0, hi = n;
    while (lo < hi) {
        int m = (lo + hi) >> 1;
        if (a[m] < v) lo = m + 1; else hi = m;
    }
    return lo;
}

__global__ __launch_bounds__(256) void pool_head_kernel(
    const unsigned short* __restrict__ h, const int* __restrict__ batch,
    const float* __restrict__ W1, const float* __restrict__ b1,
    const float* __restrict__ W2, const float* __restrict__ b2,
    float* __restrict__ out, int nNodes, int nGraphs) {
    __shared__ float psum[4][64];
    __shared__ float p[64];
    __shared__ float t64[64];
    int g = blockIdx.x;
    int tid = threadIdx.x;
    int f = tid & 63;
    int q = tid >> 6;  // wave id 0..3
    int lo = lower_bound_dev(batch, nNodes, g);
    int hi = lower_bound_dev(batch, nNodes, g + 1);
    float sum = 0.0f;
    for (int i = lo + q; i < hi; i += 4) sum += bf2f(h[(size_t)i * 64 + f]);
    psum[q][f] = sum;
    __syncthreads();
    if (tid < 64) {  // wave 0 only; intra-wave lockstep below
        float s = psum[0][f] + psum[1][f] + psum[2][f] + psum[3][f];
        float inv = 1.0f / fmaxf((float)(hi - lo), 1.0f);
        p[f] = s * inv;
        float acc = b1[f];
#pragma unroll
        for (int k = 0; k < 64; ++k) acc += p[k] * W1[k * 64 + f];
        t64[f] = fmaxf(acc, 0.0f);
        if (f < OUT_DIM) {
            float acc2 = b2[f];
#pragma unroll
            for (int k = 0; k < 64; ++k) acc2 += t64[k] * W2[k * OUT_DIM + f];
            out[g * OUT_DIM + f] = acc2;
        }
        if (g == 0 && f == 0) out[nGraphs * OUT_DIM] = 0.0f;  // trailing scalar output
    }
}

extern "C" void kernel_launch(void* const* d_in, const int* in_sizes, int n_in,
                              void* d_out, int out_size, void* d_ws, size_t ws_size,
                              hipStream_t stream) {
    const float* x      = (const float*)d_in[0];
    const int*   eidx   = (const int*)d_in[1];
    const int*   batch  = (const int*)d_in[2];
    const float* W1     = (const float*)d_in[3];
    const float* b1     = (const float*)d_in[4];
    const float* W2     = (const float*)d_in[5];
    const float* b2     = (const float*)d_in[6];
    const float* W3     = (const float*)d_in[7];
    const float* b3     = (const float*)d_in[8];
    const float* lin_W1 = (const float*)d_in[9];
    const float* lin_b1 = (const float*)d_in[10];
    const float* lin_W2 = (const float*)d_in[11];
    const float* lin_b2 = (const float*)d_in[12];
    float* out = (float*)d_out;

    const int E = in_sizes[1] / 2;
    const int N = N_NODES;
    const int NF = N * HID;
    int epb = (E + NBLK - 1) / NBLK;
    epb = (epb + 7) & ~7;  // multiple of 8 -> chunk bases stay 16B-aligned for int4 reads

    const int* src = eidx;
    const int* dst = eidx + E;

    // workspace layout
    unsigned short* buf1 = (unsigned short*)d_ws;  // hs bf16 [N,64]
    unsigned short* buf2 = buf1 + NF;              // h  bf16 [N,64]
    float* dinv = (float*)(buf2 + NF);             // [N]
    int* bhist  = (int*)(dinv + N);                // [NBLK * NB_BUCK] (in-place counts->bases)
    int* bsum   = bhist + NBLK * NB_BUCK;          // [NB_BUCK]
    int* bstart = bsum + NB_BUCK;                  // [NB_BUCK+1]
    int* rs     = bstart + NB_BUCK + 1;            // [N+1]
    int* csr_src = rs + N + 1;                     // [E]
    unsigned* pairs = (unsigned*)(csr_src + E);    // [E]

    const int TILES = (N + 63) / 64;  // 782
    const int GBLK = (N + 3) / 4;     // 12500

    // ---- atomic-free edge build ----
    p1_hist_kernel<<<NBLK, BLDT, 0, stream>>>(dst, bhist, E, epb);
    scanA_kernel<<<NB_BUCK, NBLK, 0, stream>>>(bhist, bsum);
    bscan_kernel<<<1, 1024, 0, stream>>>(bsum, bstart, NB_BUCK, E);
    p2_place_kernel<<<NBLK, BLDT, 0, stream>>>(src, dst, bstart, bhist, pairs, E, epb);
    csr_scatter2_kernel<<<NB_BUCK, 256, 0, stream>>>(pairs, bstart, rs, dinv, csr_src, N);

    // ---- layer 1 ----
    linear1_kernel<<<TILES, 256, 0, stream>>>(x, W1, dinv, buf1, N);
    gather_kernel<<<GBLK, 256, 0, stream>>>(buf1, rs, csr_src, dinv, b1, buf2, N);

    // ---- layer 2 ----
    linear_bf_kernel<<<TILES, 256, 0, stream>>>(buf2, W2, dinv, buf1, N);
    gather_kernel<<<GBLK, 256, 0, stream>>>(buf1, rs, csr_src, dinv, b2, buf2, N);

    // ---- layer 3 ----
    linear_bf_kernel<<<TILES, 256, 0, stream>>>(buf2, W3, dinv, buf1, N);
    gather_kernel<<<GBLK, 256, 0, stream>>>(buf1, rs, csr_src, dinv, b3, buf2, N);

    // ---- fused pool + head ----
    pool_head_kernel<<<N_GRAPHS, 256, 0, stream>>>(buf2, batch, lin_W1, lin_b1, lin_W2, lin_b2,
                                                   out, N, N_GRAPHS);
}